// Round 4
// baseline (387.071 us; speedup 1.0000x reference)
//
#include <hip/hip_runtime.h>

// Problem constants: x (N=64, C=256, T=64, V=50) fp32; H=16; 10 parts.
#define N_  64
#define C_  256
#define T_  64
#define V_  50
#define H_  16
#define NP_ 10
#define ROW_ (T_ * V_)          // 3200 floats per (n,c) row
#define NC_  (N_ * C_)          // 16384 rows
#define NPC_ (N_ * NP_ * C_)    // 163840 floats per ws array

typedef float f32x4 __attribute__((ext_vector_type(4)));  // native vec for NT builtins

// 1 / (T * |part p|); sizes = {5,6,4,6,4,5,6,4,6,4}  (runtime-indexed -> device global)
__device__ const float INV_CNT_D[NP_] = {
    1.f/320, 1.f/384, 1.f/256, 1.f/384, 1.f/256,
    1.f/320, 1.f/384, 1.f/256, 1.f/384, 1.f/256};

// members (source v) of each part, padded to 6 with sentinel 50
__device__ const int MEMB[NP_][6] = {
    { 0, 1, 2, 3,20,50}, { 8, 9,10,11,23,24}, {16,17,18,19,50,50},
    { 4, 5, 6, 7,21,22}, {12,13,14,15,50,50},
    {25,26,27,28,45,50}, {33,34,35,36,48,49}, {41,42,43,44,50,50},
    {29,30,31,32,46,47}, {37,38,39,40,50,50}};

// out column w -> source v (concat of PARTS) and part of w (runtime-indexed)
__device__ const int SRC_V[V_] = {
    0,1,2,3,20,  8,9,10,11,23,24,  16,17,18,19,  4,5,6,7,21,22,  12,13,14,15,
    25,26,27,28,45,  33,34,35,36,48,49,  41,42,43,44,  29,30,31,32,46,47,  37,38,39,40};
__device__ const int PART_W[V_] = {
    0,0,0,0,0, 1,1,1,1,1,1, 2,2,2,2, 3,3,3,3,3,3, 4,4,4,4,
    5,5,5,5,5, 6,6,6,6,6,6, 7,7,7,7, 8,8,8,8,8,8, 9,9,9,9};

// ---------------------------------------------------------------------------
// Kernel A (v4 — no staging): one wave per row, v-major direct accumulation.
//   lane l (<50) reads float4 xr[50t+l], t=0..15 : element k has flat index
//   200t+4l+k  ->  v = (4l+k) mod 50  CONSTANT per (lane,component).
//   Each lane keeps 4 private sum/max registers (no runtime reg indexing, no
//   LDS staging, no global->LDS round-trip). Slot s=4l+k holds the partial
//   for v = s%50; v's 4 partials live at slots {v, v+50, v+100, v+150}.
//   Tail: 2 ds_write_b128 per lane, one barrier, 20 lanes gather parts.
//   LDS 6.5 KB/block (was 51.2) -> 8 blocks/CU; zero staging barriers.
// ---------------------------------------------------------------------------
__global__ __launch_bounds__(256) void reduce_kernel(
    const float* __restrict__ x,
    float* __restrict__ avg_out,     // [(n*10+p)*256 + c]
    float* __restrict__ max_out) {
    __shared__ float sm[4][2][204];  // [wave][0=sum,1=max][slot]; 204 keeps 16B align
    const int wave = threadIdx.x >> 6;
    const int lane = threadIdx.x & 63;
    const int row  = blockIdx.x * 4 + wave;          // n*256 + c
    const float NINF = -__builtin_huge_valf();

    const float4* xr = (const float4*)(x + (size_t)row * ROW_);
    if (lane < 50) {
        float s0=0.f, s1=0.f, s2=0.f, s3=0.f;
        float m0=NINF, m1=NINF, m2=NINF, m3=NINF;
        #pragma unroll
        for (int t = 0; t < 16; ++t) {
            float4 d = xr[t * 50 + lane];
            s0 += d.x; m0 = fmaxf(m0, d.x);
            s1 += d.y; m1 = fmaxf(m1, d.y);
            s2 += d.z; m2 = fmaxf(m2, d.z);
            s3 += d.w; m3 = fmaxf(m3, d.w);
        }
        *(float4*)&sm[wave][0][4 * lane] = make_float4(s0, s1, s2, s3);
        *(float4*)&sm[wave][1][4 * lane] = make_float4(m0, m1, m2, m3);
    }
    __syncthreads();

    if (lane < 20) {
        const int p    = lane % 10;          // part
        const int kind = lane / 10;          // 0 = sum, 1 = max
        const float* base = sm[wave][kind];
        const float ident = kind ? NINF : 0.f;
        float acc = ident;
        #pragma unroll
        for (int j = 0; j < 6; ++j) {
            const int v  = MEMB[p][j];       // 50 = padding sentinel
            const bool ok = (v < 50);
            const int vv = ok ? v : 0;
            #pragma unroll
            for (int q = 0; q < 4; ++q) {
                float val = base[vv + 50 * q];
                val = ok ? val : ident;
                acc = kind ? fmaxf(acc, val) : (acc + val);
            }
        }
        const int n = row >> 8, c = row & 255;
        if (kind == 0) avg_out[(n * NP_ + p) * C_ + c] = acc * INV_CNT_D[p];
        else           max_out[(n * NP_ + p) * C_ + c] = acc;
    }
}

// ---------------------------------------------------------------------------
// Kernel B: gate[(n,p),c] = sigmoid( W2@(relu(W1@avg+b1)+relu(W1@mx+b1)) + 2*b2 )
// One block per (n,p); 256 threads.  (unchanged)
// ---------------------------------------------------------------------------
__global__ __launch_bounds__(256) void mlp_kernel(
    const float* __restrict__ avg, const float* __restrict__ mx,
    const float* __restrict__ W1, const float* __restrict__ b1,
    const float* __restrict__ W2, const float* __restrict__ b2,
    float* __restrict__ gate) {
    const int np = blockIdx.x;       // n*10 + p
    const int p  = np % NP_;
    __shared__ float vec[2][C_];
    __shared__ float partial[256];
    __shared__ float hsum[H_];

    const int t = threadIdx.x;
    vec[0][t] = avg[np * C_ + t];
    vec[1][t] = mx[np * C_ + t];
    __syncthreads();

    // partial dot: thread t = (chunk<<5) | (h<<1) | which ; 32 elements each
    const int which = t & 1, h = (t >> 1) & 15, chunk = t >> 5;
    const float* w1row = W1 + (p * H_ + h) * C_ + chunk * 32;
    const float* vv = vec[which] + chunk * 32;
    float acc = 0.f;
    #pragma unroll
    for (int k = 0; k < 32; ++k) acc += w1row[k] * vv[k];
    partial[t] = acc;
    __syncthreads();

    if (t < 32) {
        float a = b1[p * H_ + h];
        #pragma unroll
        for (int j = 0; j < 8; ++j) a += partial[t + 32 * j];
        a = fmaxf(a, 0.f);                       // relu
        if (which == 0) hsum[h] = a;
    }
    __syncthreads();
    if (t < 32 && (t & 1) == 1) {
        float a = b1[p * H_ + h];
        #pragma unroll
        for (int j = 0; j < 8; ++j) a += partial[t + 32 * j];
        hsum[h] += fmaxf(a, 0.f);
    }
    __syncthreads();

    // second layer: thread t = channel c
    const float4* w2row = (const float4*)(W2 + (p * C_ + t) * H_);
    float z = 2.f * b2[p * C_ + t];
    #pragma unroll
    for (int q = 0; q < 4; ++q) {
        float4 w = w2row[q];
        z += w.x * hsum[4*q] + w.y * hsum[4*q+1] + w.z * hsum[4*q+2] + w.w * hsum[4*q+3];
    }
    gate[np * C_ + t] = 1.f / (1.f + __expf(-z));
}

// ---------------------------------------------------------------------------
// Kernel C (v3, unchanged): swizzled single-buffer stage + table-driven gather
// emit with non-temporal float4 stores (keeps x resident in L3 for this pass).
// ---------------------------------------------------------------------------
__global__ __launch_bounds__(256) void scale_kernel(
    const float* __restrict__ x, const float* __restrict__ gate,
    float* __restrict__ out) {
    __shared__ float  lx[ROW_];      // 12.8 KB swizzled staged row
    __shared__ float4 tq[25];        // packed {dsv,gv} pairs, indexed by w>>1

    const int row = blockIdx.x;              // n*256 + c
    const int n = row >> 8, c = row & 255;
    const int tid = threadIdx.x;

    // ---- build permutation/gate table (50 threads; component writes, no race)
    if (tid < V_) {
        const int w = tid;
        const float g = gate[(n * NP_ + PART_W[w]) * C_ + c];
        const int dsv = SRC_V[w] - w;
        float* t4 = (float*)&tq[w >> 1];
        t4[(w & 1) * 2 + 0] = __int_as_float(dsv);
        t4[(w & 1) * 2 + 1] = g;
    }

    // ---- issue all global loads for the row (coalesced float4)
    const float4* src = (const float4*)(x + (size_t)row * ROW_);
    float4 d0 = src[tid];
    float4 d1 = src[tid + 256];
    float4 d2 = src[tid + 512];
    float4 d3 = {};
    if (tid < 32) d3 = src[tid + 768];

    // ---- stage with XOR swizzle (scalar writes, dense & bijective)
    {
        float vals[16] = {d0.x,d0.y,d0.z,d0.w, d1.x,d1.y,d1.z,d1.w,
                          d2.x,d2.y,d2.z,d2.w, d3.x,d3.y,d3.z,d3.w};
        #pragma unroll
        for (int r = 0; r < 4; ++r) {
            if (r == 3 && tid >= 32) break;
            const int f0 = (tid + 256 * r) * 4;
            #pragma unroll
            for (int k = 0; k < 4; ++k) {
                const int f = f0 + k;
                lx[f ^ ((f >> 5) & 3)] = vals[r * 4 + k];
            }
        }
    }
    __syncthreads();                 // lx + tq ready

    // ---- emit: per output quad, 2 b128 table reads + 4 swizzled gathers
    f32x4* dst = (f32x4*)(out + (size_t)row * ROW_);
    int w0 = (tid << 2) % 50u;       // (4*tid) % 50 ; even
    #pragma unroll
    for (int rep = 0; rep < 4; ++rep) {
        if (rep == 3 && tid >= 32) break;
        const int u  = tid + 256 * rep;      // output float4 index in row
        const int e0 = u * 4;                // output flat element index
        int wB = w0 + 2; if (wB >= V_) wB -= V_;
        const float4 tA = tq[w0 >> 1];
        const float4 tB = tq[wB >> 1];
        const int f0 = e0 + 0 + __float_as_int(tA.x);
        const int f1 = e0 + 1 + __float_as_int(tA.z);
        const int f2 = e0 + 2 + __float_as_int(tB.x);
        const int f3 = e0 + 3 + __float_as_int(tB.z);
        f32x4 o;
        o.x = lx[f0 ^ ((f0 >> 5) & 3)] * tA.y;
        o.y = lx[f1 ^ ((f1 >> 5) & 3)] * tA.w;
        o.z = lx[f2 ^ ((f2 >> 5) & 3)] * tB.y;
        o.w = lx[f3 ^ ((f3 >> 5) & 3)] * tB.w;
        __builtin_nontemporal_store(o, &dst[u]);
        w0 += 24; if (w0 >= V_) w0 -= V_;    // (w0 + 1024) % 50
    }
}

// ---------------------------------------------------------------------------
extern "C" void kernel_launch(void* const* d_in, const int* in_sizes, int n_in,
                              void* d_out, int out_size, void* d_ws, size_t ws_size,
                              hipStream_t stream) {
    const float* x  = (const float*)d_in[0];
    const float* W1 = (const float*)d_in[1];
    const float* b1 = (const float*)d_in[2];
    const float* W2 = (const float*)d_in[3];
    const float* b2 = (const float*)d_in[4];
    float* out = (float*)d_out;

    float* avg  = (float*)d_ws;            // NPC_ floats
    float* mx   = avg + NPC_;              // NPC_ floats
    float* gate = mx + NPC_;               // NPC_ floats

    reduce_kernel<<<NC_ / 4, 256, 0, stream>>>(x, avg, mx);
    mlp_kernel<<<N_ * NP_, 256, 0, stream>>>(avg, mx, W1, b1, W2, b2, gate);
    scale_kernel<<<NC_, 256, 0, stream>>>(x, gate, out);
}